// Round 3
// baseline (558.411 us; speedup 1.0000x reference)
//
#include <hip/hip_runtime.h>
#include <math.h>

#define B 2
#define M 1024
#define V 300
#define C 128
#define HID 128
#define BIN 256
#define H 384
#define W 512
#define QIN (C + 7)   // 135
#define TM 8          // seeds per block

// ---------------------------------------------------------------------------
// Kernel 1: anchor MLP  a[v,:]=relu(vd@Wa1+ba1)@Wa2+ba2 -> a_ws (VxHID) and
//           aT_ws (HIDxV);  bias[v]=(relu(vd@Wb1+bb1)@Wb2+bb2)[0].
// ---------------------------------------------------------------------------
__global__ __launch_bounds__(HID) void anchor_kernel(
    const float* __restrict__ view_dirs,
    const float* __restrict__ Wa1, const float* __restrict__ ba1,
    const float* __restrict__ Wa2, const float* __restrict__ ba2,
    const float* __restrict__ Wb1, const float* __restrict__ bb1,
    const float* __restrict__ Wb2, const float* __restrict__ bb2,
    float* __restrict__ a_out, float* __restrict__ aT_out,
    float* __restrict__ bias_out) {
  const int v = blockIdx.x;
  const int t = threadIdx.x;
  __shared__ float h1[HID];

  const float vd0 = view_dirs[v * 3 + 0];
  const float vd1 = view_dirs[v * 3 + 1];
  const float vd2 = view_dirs[v * 3 + 2];

  float h = vd0 * Wa1[0 * HID + t] + vd1 * Wa1[1 * HID + t] + vd2 * Wa1[2 * HID + t] + ba1[t];
  h1[t] = fmaxf(h, 0.0f);

  if (t < 64) {
    float x = vd0 * Wb1[0 * 64 + t] + vd1 * Wb1[1 * 64 + t] + vd2 * Wb1[2 * 64 + t] + bb1[t];
    x = fmaxf(x, 0.0f) * Wb2[t];
#pragma unroll
    for (int o = 32; o > 0; o >>= 1) x += __shfl_down(x, o, 64);
    if (t == 0) bias_out[v] = x + bb2[0];
  }
  __syncthreads();

  float acc = ba2[t];
#pragma unroll 8
  for (int k = 0; k < HID; ++k) acc += h1[k] * Wa2[k * HID + t];
  a_out[v * HID + t] = acc;
  aT_out[(size_t)t * V + v] = acc;
}

// ---------------------------------------------------------------------------
// Kernel 2: TM=8 seeds per block, 256 threads. Register-blocked MLPs:
// each weight element loaded once, reused for 4 seeds per thread-group.
// ---------------------------------------------------------------------------
__global__ __launch_bounds__(256) void seed_kernel(
    const float* __restrict__ seed_features, const int* __restrict__ token_sel_idx,
    const float* __restrict__ Kmat, const float* __restrict__ depth_map,
    const float* __restrict__ depth_prob, const float* __restrict__ view_dirs,
    const float* __restrict__ Wq1, const float* __restrict__ bq1,
    const float* __restrict__ Wq2, const float* __restrict__ bq2,
    const float* __restrict__ Wr1, const float* __restrict__ br1,
    const float* __restrict__ Wr2, const float* __restrict__ br2,
    const float* __restrict__ a_ws, const float* __restrict__ aT_ws,
    const float* __restrict__ bias_ws,
    float* __restrict__ out_view_score, float* __restrict__ out_top_inds,
    float* __restrict__ out_top_xyz, float* __restrict__ out_rot,
    float* __restrict__ out_res) {
  const int bm0 = blockIdx.x * TM;
  const int b = bm0 / M;
  const int m0 = bm0 - b * M;
  const int t = threadIdx.x;
  const int lane = t & 63;
  const int wv = t >> 6;

  __shared__ float qin[TM][QIN + 1];     // 8 x 136
  __shared__ float hs[TM][HID];
  __shared__ float qs[TM][HID];
  __shared__ float sc_s[TM][304];
  __shared__ float atop[TM][HID];
  __shared__ float ered[TM];
  __shared__ int   sidx[TM];
  __shared__ int   sbest[TM];

  if (t < TM) sidx[t] = token_sel_idx[bm0 + t];

  // ---- seed features: s-fast layout -> 8 consecutive floats per c ----
  for (int i = t; i < TM * C; i += 256) {
    const int s = i & 7;
    const int c = i >> 3;
    qin[s][c] = seed_features[((size_t)b * C + c) * M + m0 + s];
  }
  __syncthreads();

  // ---- entropy: 32 threads per seed, 8 bins each ----
  {
    const int es = t >> 5;     // seed 0..7
    const int sub = t & 31;
    const float* dp = depth_prob + (size_t)b * BIN * H * W + sidx[es];
    float e = 0.0f;
#pragma unroll
    for (int j = 0; j < 8; ++j) {
      const float p = fmaxf(dp[(size_t)(sub + 32 * j) * (H * W)], 1e-8f);
      e += p * logf(p);
    }
#pragma unroll
    for (int o = 16; o > 0; o >>= 1) e += __shfl_down(e, o, 32);
    if (sub == 0) ered[es] = e;
  }
  __syncthreads();

  // ---- threads 0..7: uncertainty, normal, ray for seed t ----
  if (t < TM) {
    const int idx = sidx[t];
    float uncert = (-ered[t]) / 5.5451774444795623f;  // log(256)
    uncert = fminf(fmaxf(uncert, 0.0f), 1.0f);

    const float fx = Kmat[b * 9 + 0], fy = Kmat[b * 9 + 4];
    const float cx = Kmat[b * 9 + 2], cy = Kmat[b * 9 + 5];
    const int w = idx % W;
    const int h = idx / W;
    const int hc = min(max(h, 1), H - 2);
    const int wc = min(max(w, 1), W - 2);

    const float* dm = depth_map + (size_t)b * H * W;
    const float zl = dm[hc * W + (wc - 1)];
    const float zr = dm[hc * W + (wc + 1)];
    const float zu = dm[(hc - 1) * W + wc];
    const float zd = dm[(hc + 1) * W + wc];

    const float dxx = (wc + 1 - cx) / fx * zr - (wc - 1 - cx) / fx * zl;
    const float dxy = (hc - cy) / fy * zr - (hc - cy) / fy * zl;
    const float dxz = zr - zl;
    const float dyx = (wc - cx) / fx * zd - (wc - cx) / fx * zu;
    const float dyy = (hc + 1 - cy) / fy * zd - (hc - 1 - cy) / fy * zu;
    const float dyz = zd - zu;

    float nx = dxy * dyz - dxz * dyy;
    float ny = dxz * dyx - dxx * dyz;
    float nz = dxx * dyy - dxy * dyx;
    const float nn = fmaxf(sqrtf(nx * nx + ny * ny + nz * nz), 1e-6f);
    const float sc = (1.0f - uncert) / nn;

    const float rx = ((float)w - cx) / fx;
    const float ry = ((float)h - cy) / fy;
    const float rn = fmaxf(sqrtf(rx * rx + ry * ry + 1.0f), 1e-12f);

    qin[t][128] = rx / rn;
    qin[t][129] = ry / rn;
    qin[t][130] = 1.0f / rn;
    qin[t][131] = nx * sc;
    qin[t][132] = ny * sc;
    qin[t][133] = nz * sc;
    qin[t][134] = uncert;
  }
  __syncthreads();

  // ---- q MLP layer 1: col = t&127 owns output col, 4 seeds per group ----
  const int col = t & 127;
  const int grp = (t >> 7) * 4;   // seed base 0 or 4
  {
    float acc0 = bq1[col], acc1 = acc0, acc2 = acc0, acc3 = acc0;
#pragma unroll 5
    for (int i = 0; i < QIN; ++i) {
      const float w = Wq1[i * HID + col];
      acc0 += qin[grp + 0][i] * w;
      acc1 += qin[grp + 1][i] * w;
      acc2 += qin[grp + 2][i] * w;
      acc3 += qin[grp + 3][i] * w;
    }
    hs[grp + 0][col] = fmaxf(acc0, 0.0f);
    hs[grp + 1][col] = fmaxf(acc1, 0.0f);
    hs[grp + 2][col] = fmaxf(acc2, 0.0f);
    hs[grp + 3][col] = fmaxf(acc3, 0.0f);
  }
  __syncthreads();

  // ---- q MLP layer 2 ----
  {
    float acc0 = bq2[col], acc1 = acc0, acc2 = acc0, acc3 = acc0;
#pragma unroll 8
    for (int k = 0; k < HID; ++k) {
      const float w = Wq2[k * HID + col];
      acc0 += hs[grp + 0][k] * w;
      acc1 += hs[grp + 1][k] * w;
      acc2 += hs[grp + 2][k] * w;
      acc3 += hs[grp + 3][k] * w;
    }
    qs[grp + 0][col] = fmaxf(acc0, 0.0f);
    qs[grp + 1][col] = fmaxf(acc1, 0.0f);
    qs[grp + 2][col] = fmaxf(acc2, 0.0f);
    qs[grp + 3][col] = fmaxf(acc3, 0.0f);
  }
  __syncthreads();

  // ---- logits: thread handles view t (and t+256 if t<44), all 8 seeds ----
  const float rsq = 0.08838834764831845f;  // 1/sqrt(128)
  for (int v = t; v < V; v += 256) {
    float d[TM];
#pragma unroll
    for (int s = 0; s < TM; ++s) d[s] = 0.0f;
#pragma unroll 4
    for (int k = 0; k < HID; ++k) {
      const float av = aT_ws[(size_t)k * V + v];
#pragma unroll
      for (int s = 0; s < TM; ++s) d[s] += qs[s][k] * av;
    }
    const float bsv = bias_ws[v];
#pragma unroll
    for (int s = 0; s < TM; ++s) {
      const float scv = 1.0f / (1.0f + expf(-(d[s] * rsq + bsv)));
      sc_s[s][v] = scv;
      out_view_score[(size_t)(bm0 + s) * V + v] = scv;
    }
  }
  __syncthreads();

  // ---- per-seed argmax (first-index ties): wave wv handles seeds wv, wv+4 ----
  for (int s = wv; s < TM; s += 4) {
    float bv = -1.0f;
    int bi = 0;
    for (int v = lane; v < V; v += 64) {
      const float x = sc_s[s][v];
      if (x > bv) { bv = x; bi = v; }
    }
#pragma unroll
    for (int o = 32; o > 0; o >>= 1) {
      const float ov = __shfl_down(bv, o, 64);
      const int oi = __shfl_down(bi, o, 64);
      if (ov > bv || (ov == bv && oi < bi)) { bv = ov; bi = oi; }
    }
    if (lane == 0) sbest[s] = bi;
  }
  __syncthreads();

  // ---- tops + rot: thread s < 8 ----
  if (t < TM) {
    const int best = sbest[t];
    const int bm = bm0 + t;
    out_top_inds[bm] = (float)best;
    const float vx = view_dirs[best * 3 + 0];
    const float vy = view_dirs[best * 3 + 1];
    const float vz = view_dirs[best * 3 + 2];
    out_top_xyz[(size_t)bm * 3 + 0] = vx;
    out_top_xyz[(size_t)bm * 3 + 1] = vy;
    out_top_xyz[(size_t)bm * 3 + 2] = vz;

    float ax0 = -vx, ax1 = -vy, ax2 = -vz;
    float ay0 = vy, ay1 = -vx, ay2 = 0.0f;
    const float nyn = sqrtf(ay0 * ay0 + ay1 * ay1);
    if (nyn < 1e-8f) {
      ay0 = 0.0f; ay1 = 1.0f; ay2 = 0.0f;
    } else {
      const float d = fmaxf(nyn, 1e-8f);
      ay0 /= d; ay1 /= d;
    }
    const float an = fmaxf(sqrtf(ax0 * ax0 + ax1 * ax1 + ax2 * ax2), 1e-8f);
    ax0 /= an; ax1 /= an; ax2 /= an;
    const float az0 = ax1 * ay2 - ax2 * ay1;
    const float az1 = ax2 * ay0 - ax0 * ay2;
    const float az2 = ax0 * ay1 - ax1 * ay0;
    float* R = out_rot + (size_t)bm * 9;
    R[0] = ax0; R[1] = ay0; R[2] = az0;
    R[3] = ax1; R[4] = ay1; R[5] = az1;
    R[6] = ax2; R[7] = ay2; R[8] = az2;
  }

  // ---- gather a[best] rows into LDS ----
  for (int i = t; i < TM * HID; i += 256) {
    const int s = i >> 7;
    const int k = i & 127;
    atop[s][k] = a_ws[(size_t)sbest[s] * HID + k];
  }
  __syncthreads();

  // ---- residual MLP layer 1 ----
  {
    float acc0 = br1[col], acc1 = acc0, acc2 = acc0, acc3 = acc0;
#pragma unroll 8
    for (int k = 0; k < HID; ++k) {
      const float w = Wr1[k * HID + col];
      acc0 += (qs[grp + 0][k] + atop[grp + 0][k]) * w;
      acc1 += (qs[grp + 1][k] + atop[grp + 1][k]) * w;
      acc2 += (qs[grp + 2][k] + atop[grp + 2][k]) * w;
      acc3 += (qs[grp + 3][k] + atop[grp + 3][k]) * w;
    }
    hs[grp + 0][col] = fmaxf(acc0, 0.0f);
    hs[grp + 1][col] = fmaxf(acc1, 0.0f);
    hs[grp + 2][col] = fmaxf(acc2, 0.0f);
    hs[grp + 3][col] = fmaxf(acc3, 0.0f);
  }
  __syncthreads();

  // ---- residual MLP layer 2 + strided output write (B,C,M) ----
  {
    float acc0 = br2[col], acc1 = acc0, acc2 = acc0, acc3 = acc0;
#pragma unroll 8
    for (int k = 0; k < HID; ++k) {
      const float w = Wr2[k * HID + col];
      acc0 += hs[grp + 0][k] * w;
      acc1 += hs[grp + 1][k] * w;
      acc2 += hs[grp + 2][k] * w;
      acc3 += hs[grp + 3][k] * w;
    }
    float* o = out_res + ((size_t)b * C + col) * M + m0 + grp;
    o[0] = acc0; o[1] = acc1; o[2] = acc2; o[3] = acc3;
  }
}

// ---------------------------------------------------------------------------
extern "C" void kernel_launch(void* const* d_in, const int* in_sizes, int n_in,
                              void* d_out, int out_size, void* d_ws, size_t ws_size,
                              hipStream_t stream) {
  const float* seed  = (const float*)d_in[0];
  const int*   tok   = (const int*)d_in[1];
  const float* Km    = (const float*)d_in[2];
  const float* dmap  = (const float*)d_in[3];
  const float* dprob = (const float*)d_in[4];
  const float* vdirs = (const float*)d_in[5];
  const float* Wq1 = (const float*)d_in[6];  const float* bq1 = (const float*)d_in[7];
  const float* Wq2 = (const float*)d_in[8];  const float* bq2 = (const float*)d_in[9];
  const float* Wa1 = (const float*)d_in[10]; const float* ba1 = (const float*)d_in[11];
  const float* Wa2 = (const float*)d_in[12]; const float* ba2 = (const float*)d_in[13];
  const float* Wb1 = (const float*)d_in[14]; const float* bb1 = (const float*)d_in[15];
  const float* Wb2 = (const float*)d_in[16]; const float* bb2 = (const float*)d_in[17];
  const float* Wr1 = (const float*)d_in[18]; const float* br1 = (const float*)d_in[19];
  const float* Wr2 = (const float*)d_in[20]; const float* br2 = (const float*)d_in[21];

  float* out = (float*)d_out;
  float* vs  = out;                                  // view_score (B,M,V)
  float* ti  = vs + (size_t)B * M * V;               // top_inds  (B,M)
  float* tx  = ti + (size_t)B * M;                   // top_xyz   (B,M,3)
  float* rot = tx + (size_t)B * M * 3;               // rot       (B,M,3,3)
  float* rf  = rot + (size_t)B * M * 9;              // res_feat  (B,C,M)

  float* a_ws    = (float*)d_ws;                     // V*HID
  float* aT_ws   = a_ws + (size_t)V * HID;           // HID*V
  float* bias_ws = aT_ws + (size_t)HID * V;          // V

  anchor_kernel<<<V, HID, 0, stream>>>(vdirs, Wa1, ba1, Wa2, ba2, Wb1, bb1, Wb2, bb2,
                                       a_ws, aT_ws, bias_ws);
  seed_kernel<<<(B * M) / TM, 256, 0, stream>>>(seed, tok, Km, dmap, dprob, vdirs,
                                                Wq1, bq1, Wq2, bq2, Wr1, br1, Wr2, br2,
                                                a_ws, aT_ws, bias_ws, vs, ti, tx, rot, rf);
}